// Round 7
// baseline (243.456 us; speedup 1.0000x reference)
//
#include <hip/hip_runtime.h>
#include <math.h>

// Problem constants
#define T_TOKENS 16384
#define HID      2048
#define NE       64
#define TOPK     8
// Tiling
#define TM       32              // tokens per block -> grid 512 = 2 blocks/CU
#define BK       128             // k-chunk
#define NCH      (HID / BK)      // 16
// A LDS geometry: row = 128 bf16 + 8 pad = 272 B; 272 mod 128 = 16 ->
// b128 frag reads hit each 16B bank-group exactly 2x per quarter-wave (free).
#define RSTR     272
#define A_SPL    (TM * RSTR)     // 8704  : one A split plane
#define ABUF     (3 * A_SPL)     // 26112 : one buffer (3 planes)
#define LDS_BYTES (2 * ABUF)     // 52224 : double-buffered -> 2 blocks/CU

// B fragment store in workspace (short8 = 16 B units):
//   idx = plane*16384 + kstep*256 + etile*64 + lane
// lane holds W[etile*16 + (lane&15)][kstep*32 + (lane>>4)*8 .. +7]
#define WS_SHORT8 49152          // 786432 B workspace

typedef float    f32x4  __attribute__((ext_vector_type(4)));
typedef short    short8 __attribute__((ext_vector_type(8)));
typedef unsigned uint4v __attribute__((ext_vector_type(4)));
typedef unsigned uint2v __attribute__((ext_vector_type(2)));

#define MFMA16(A, B, C) __builtin_amdgcn_mfma_f32_16x16x32_bf16((A), (B), (C), 0, 0, 0)

// RNE f2bf (probe only)
static __device__ __forceinline__ unsigned short f2bf(float x) {
    unsigned u = __builtin_bit_cast(unsigned, x);
    return (unsigned short)((u + 0x7FFFu + ((u >> 16) & 1u)) >> 16);
}

// 3-plane bf16 split of 4 floats -> 3 x uint2 (bit-identical element math to
// the R4-R6 split8: round-half-away masks, plane2 truncates).
static __device__ __forceinline__ void split4(const float4 v,
                                              uint2v& p0, uint2v& p1, uint2v& p2)
{
    const float x[4] = {v.x, v.y, v.z, v.w};
    #pragma unroll
    for (int j = 0; j < 2; ++j) {
        const float xe = x[2 * j], xo = x[2 * j + 1];
        const unsigned ue  = __builtin_bit_cast(unsigned, xe);
        const unsigned m0e = (ue + 0x8000u) & 0xFFFF0000u;
        const float    r1e = xe - __builtin_bit_cast(float, m0e);
        const unsigned u1e = __builtin_bit_cast(unsigned, r1e);
        const unsigned m1e = (u1e + 0x8000u) & 0xFFFF0000u;
        const float    r2e = r1e - __builtin_bit_cast(float, m1e);
        const unsigned u2e = __builtin_bit_cast(unsigned, r2e);
        const unsigned uo  = __builtin_bit_cast(unsigned, xo);
        const unsigned m0o = (uo + 0x8000u) & 0xFFFF0000u;
        const float    r1o = xo - __builtin_bit_cast(float, m0o);
        const unsigned u1o = __builtin_bit_cast(unsigned, r1o);
        const unsigned m1o = (u1o + 0x8000u) & 0xFFFF0000u;
        const float    r2o = r1o - __builtin_bit_cast(float, m1o);
        const unsigned u2o = __builtin_bit_cast(unsigned, r2o);
        p0[j] = m0o | (m0e >> 16);
        p1[j] = m1o | (m1e >> 16);
        p2[j] = (u2o & 0xFFFF0000u) | (u2e >> 16);
    }
}

// ---- pre-pass: split weight once into 3 bf16 planes in B-frag layout ----
__global__ __launch_bounds__(256) void split_weight_kernel(
    const float* __restrict__ weight, uint4v* __restrict__ ws)
{
    const int n = blockIdx.x;      // expert 0..63
    const int o = threadIdx.x;     // k-octet 0..255
    const float4 w0 = *(const float4*)&weight[(size_t)n * HID + o * 8];
    const float4 w1 = *(const float4*)&weight[(size_t)n * HID + o * 8 + 4];
    uint2v a0, a1, a2, b0, b1, b2;
    split4(w0, a0, a1, a2);
    split4(w1, b0, b1, b2);
    const int t    = o >> 2;
    const int lane = (o & 3) * 16 + (n & 15);
    const int e    = n >> 4;
    const int base = t * 256 + e * 64 + lane;
    ws[base]         = uint4v{a0[0], a0[1], b0[0], b0[1]};
    ws[base + 16384] = uint4v{a1[0], a1[1], b1[0], b1[1]};
    ws[base + 32768] = uint4v{a2[0], a2[1], b2[0], b2[1]};
}

__global__ __launch_bounds__(256, 2) void router_kernel(
    const float* __restrict__ hidden,   // [T_TOKENS, HID] f32
    const short8* __restrict__ bfrag,   // pre-split B planes (frag layout)
    float* __restrict__ out_logits,     // [T_TOKENS, NE]
    float* __restrict__ out_vals,       // [T_TOKENS, TOPK]
    float* __restrict__ out_idxf)       // [T_TOKENS, TOPK]
{
    __shared__ __align__(16) char smem[LDS_BYTES];
    double (*lg)[NE + 1] = reinterpret_cast<double(*)[NE + 1]>(smem);

    const int tid  = threadIdx.x;
    const int tok0 = blockIdx.x * TM;
    const int lane = tid & 63;
    const int wave = tid >> 6;   // 0..3 == expert tile of this wave

    const int fr = lane & 15;
    const int fk = lane >> 4;

    // ---- runtime D-layout probe (verified R3-R6) ----
    int rowmap[4], colmap[4];
    {
        const unsigned short mb = f2bf((float)fr);
        const unsigned short ob = f2bf(0.03125f);
        short8 vm, vo;
        #pragma unroll
        for (int j = 0; j < 8; ++j) { vm[j] = (short)mb; vo[j] = (short)ob; }
        const f32x4 z = {0.f, 0.f, 0.f, 0.f};
        const f32x4 pr = MFMA16(vm, vo, z);
        const f32x4 pc = MFMA16(vo, vm, z);
        #pragma unroll
        for (int i = 0; i < 4; ++i) {
            rowmap[i] = (int)(pr[i] + 0.5f);
            colmap[i] = (int)(pc[i] + 0.5f);
        }
    }

    // A staging map (quad-interleaved, 16-line global instructions):
    // thread t owns row (t>>3), float4 quads at cols 4*(t&7) + 32*q.
    // Per instruction: lanes 0-7 read 128 B contiguous -> 16 lines/instr.
    const int ar = tid >> 3;
    const int ag = tid & 7;
    const float* aG = hidden + (size_t)(tok0 + ar) * HID + 4 * ag;
    const int aWOff = ar * RSTR + 8 * ag;        // + 64*q per quad (bytes)

    // B frag pointer: this wave's expert tile
    const short8* bP = bfrag + wave * 64 + lane;

    // A frag read bases (bytes within buffer) for the 2 token-frags
    const int aOff0 = fr * RSTR + fk * 16;
    const int aOff1 = (16 + fr) * RSTR + fk * 16;

    const f32x4 z4 = {0.f, 0.f, 0.f, 0.f};
    f32x4 acch[2]    = {z4, z4};         // a0*b0 per token-frag (4-chain)
    f32x4 accl[2][2] = {{z4, z4}, {z4, z4}}; // corrections, 2 chains/frag (10/10)
    double accd[2][4] = {{0, 0, 0, 0}, {0, 0, 0, 0}};

    float4 pa[4];
    short8 Bcur0, Bcur1, Bcur2;

#define STAGE_A(dstbase) do {                                                     \
    uint2v q0, q1, q2;                                                            \
    char* aW_ = (dstbase) + aWOff;                                                \
    _Pragma("unroll")                                                             \
    for (int q_ = 0; q_ < 4; ++q_) {                                              \
        split4(pa[q_], q0, q1, q2);                                               \
        *(uint2v*)(aW_             + 64 * q_) = q0;                               \
        *(uint2v*)(aW_ +   A_SPL   + 64 * q_) = q1;                               \
        *(uint2v*)(aW_ + 2*A_SPL   + 64 * q_) = q2;                               \
    }                                                                             \
} while (0)

    // ---- prologue: stage chunk 0 + preload B(t=0) ----
    #pragma unroll
    for (int q = 0; q < 4; ++q) pa[q] = *(const float4*)(aG + 32 * q);
    STAGE_A(smem);
    Bcur0 = bP[0];
    Bcur1 = bP[16384];
    Bcur2 = bP[32768];
    __syncthreads();

    for (int c = 0; c < NCH; ++c) {
        const char* bufc = smem + (c & 1) * ABUF;

        // A frags for st=0
        short8 A00 = *(const short8*)(bufc + aOff0);
        short8 A01 = *(const short8*)(bufc + A_SPL + aOff0);
        short8 A02 = *(const short8*)(bufc + 2 * A_SPL + aOff0);
        short8 A10 = *(const short8*)(bufc + aOff1);
        short8 A11 = *(const short8*)(bufc + A_SPL + aOff1);
        short8 A12 = *(const short8*)(bufc + 2 * A_SPL + aOff1);

        // T14: issue next chunk's A global loads (hide under MFMA phase)
        if (c + 1 < NCH) {
            const int off = (c + 1) * BK;
            #pragma unroll
            for (int q = 0; q < 4; ++q) pa[q] = *(const float4*)(aG + off + 32 * q);
        }

        // ---- 4 k-steps, explicit 1-step pipeline ----
        #pragma unroll
        for (int st = 0; st < 4; ++st) {
            short8 An00, An01, An02, An10, An11, An12;
            short8 Bn0, Bn1, Bn2;
            if (st < 3) {
                const int ao = (st + 1) * 64;
                An00 = *(const short8*)(bufc + aOff0 + ao);
                An01 = *(const short8*)(bufc + A_SPL + aOff0 + ao);
                An02 = *(const short8*)(bufc + 2 * A_SPL + aOff0 + ao);
                An10 = *(const short8*)(bufc + aOff1 + ao);
                An11 = *(const short8*)(bufc + A_SPL + aOff1 + ao);
                An12 = *(const short8*)(bufc + 2 * A_SPL + aOff1 + ao);
                const int t = c * 4 + st + 1;
                Bn0 = bP[t * 256];
                Bn1 = bP[t * 256 + 16384];
                Bn2 = bP[t * 256 + 32768];
            } else if (c + 1 < NCH) {
                const int t = (c + 1) * 4;
                Bn0 = bP[t * 256];
                Bn1 = bP[t * 256 + 16384];
                Bn2 = bP[t * 256 + 32768];
            }

            // 12 MFMAs; corrections alternate between 2 chains per frag
            // (step parity) so no accumulator chain exceeds 10 per chunk.
            const int e0 = st & 1, e1 = e0 ^ 1;
            acch[0]     = MFMA16(A00, Bcur0, acch[0]);
            accl[0][e0] = MFMA16(A00, Bcur1, accl[0][e0]);
            accl[0][e1] = MFMA16(A01, Bcur0, accl[0][e1]);
            accl[0][e0] = MFMA16(A01, Bcur1, accl[0][e0]);
            accl[0][e1] = MFMA16(A00, Bcur2, accl[0][e1]);
            accl[0][e0] = MFMA16(A02, Bcur0, accl[0][e0]);
            acch[1]     = MFMA16(A10, Bcur0, acch[1]);
            accl[1][e0] = MFMA16(A10, Bcur1, accl[1][e0]);
            accl[1][e1] = MFMA16(A11, Bcur0, accl[1][e1]);
            accl[1][e0] = MFMA16(A11, Bcur1, accl[1][e0]);
            accl[1][e1] = MFMA16(A10, Bcur2, accl[1][e1]);
            accl[1][e0] = MFMA16(A12, Bcur0, accl[1][e0]);

            if (st < 3) {
                A00 = An00; A01 = An01; A02 = An02;
                A10 = An10; A11 = An11; A12 = An12;
                Bcur0 = Bn0; Bcur1 = Bn1; Bcur2 = Bn2;
            } else if (c + 1 < NCH) {
                Bcur0 = Bn0; Bcur1 = Bn1; Bcur2 = Bn2;
            }
        }

        // ---- span dump: hi-term f32 acc -> f64, reset ----
        #pragma unroll
        for (int f = 0; f < 2; ++f) {
            #pragma unroll
            for (int i = 0; i < 4; ++i) accd[f][i] += (double)acch[f][i];
            acch[f] = z4;
        }

        // ---- split + write next chunk into the other buffer, ONE barrier ----
        if (c + 1 < NCH) {
            STAGE_A(smem + ((c & 1) ^ 1) * ABUF);
        }
        __syncthreads();
    }

    // ---- epilogue: logits (f64 = hi-f64 + sum of correction chains) ----
    #pragma unroll
    for (int f = 0; f < 2; ++f) {
        #pragma unroll
        for (int i = 0; i < 4; ++i) {
            const int trow = f * 16 + rowmap[i];
            const int tok  = tok0 + trow;
            const int e0   = wave * 16 + colmap[i];
            const double l0 = accd[f][i] + (double)accl[f][0][i]
                                         + (double)accl[f][1][i];
            out_logits[(size_t)tok * NE + e0] = (float)l0;
            lg[trow][e0] = l0;
        }
    }
    __syncthreads();

    // ---- per-token top-8 + renormalized softmax, 2 tokens per wave ----
    // Lane l: half = l>>5 picks the token; lane holds experts (l&31), (l&31)+32.
    // 5 xor levels (<=16) reduce within the 32-lane half; winner expert via
    // 2 ballots with slot0 priority == lowest-expert tie-break (matches R3-R6).
    {
        const int elo  = lane & 31;
        const int half = lane >> 5;
        for (int tp = wave; tp < TM / 2; tp += 4) {
            const int tok_r = tp * 2 + half;
            double cur0 = lg[tok_r][elo];
            double cur1 = lg[tok_r][elo + 32];
            double first = 0.0;
            float  s = 0.f, myv = 0.f;
            int myi = 0;
            #pragma unroll
            for (int i = 0; i < TOPK; ++i) {
                double mv = cur1 > cur0 ? cur1 : cur0;
                #pragma unroll
                for (int off = 16; off; off >>= 1) {
                    const double ov = __shfl_xor(mv, off);
                    mv = ov > mv ? ov : mv;
                }
                const unsigned long long b0 = __ballot(cur0 == mv);
                const unsigned long long b1 = __ballot(cur1 == mv);
                const unsigned m0h = (unsigned)(half ? (b0 >> 32) : b0);
                const unsigned m1h = (unsigned)(half ? (b1 >> 32) : b1);
                const int mi = m0h ? (__ffs(m0h) - 1) : (32 + __ffs(m1h) - 1);
                if (i == 0) first = mv;
                const float e = expf((float)(mv - first));
                s += e;
                if (elo == i)      { myv = e; myi = mi; }
                if (mi == elo)          cur0 = -INFINITY;
                else if (mi == elo + 32) cur1 = -INFINITY;
            }
            if (elo < TOPK) {
                const int tok = tok0 + tok_r;
                out_vals[(size_t)tok * TOPK + elo] = myv / s;
                out_idxf[(size_t)tok * TOPK + elo] = (float)myi;
            }
        }
    }
}

extern "C" void kernel_launch(void* const* d_in, const int* in_sizes, int n_in,
                              void* d_out, int out_size, void* d_ws, size_t ws_size,
                              hipStream_t stream) {
    const float* hidden = (const float*)d_in[0];   // [16384, 2048] f32
    const float* weight = (const float*)d_in[1];   // [64, 2048] f32

    float* out        = (float*)d_out;
    float* out_logits = out;
    float* out_vals   = out + (size_t)T_TOKENS * NE;
    float* out_idxf   = out + (size_t)T_TOKENS * NE + (size_t)T_TOKENS * TOPK;

    uint4v* ws = (uint4v*)d_ws;   // needs 786432 B of workspace

    hipLaunchKernelGGL(split_weight_kernel, dim3(NE), dim3(256), 0, stream,
                       weight, ws);
    hipLaunchKernelGGL(router_kernel, dim3(T_TOKENS / TM), dim3(256), 0, stream,
                       hidden, (const short8*)ws, out_logits, out_vals, out_idxf);
}

// Round 10
// 219.193 us; speedup vs baseline: 1.1107x; 1.1107x over previous
//
#include <hip/hip_runtime.h>
#include <math.h>

// Problem constants
#define T_TOKENS 16384
#define HID      2048
#define NE       64
#define TOPK     8
// Tiling
#define TM       32              // tokens per block -> grid 512 = 2 blocks/CU
#define BK       128             // k-chunk
#define NCH      (HID / BK)      // 16
// A LDS geometry: row = 128 bf16 + 8 pad = 272 B; 272 mod 128 = 16 ->
// b128 frag reads hit each 16B bank-group exactly 2x per quarter-wave (free).
#define RSTR     272
#define A_SPL    (TM * RSTR)     // 8704  : one A split plane
#define ABUF     (3 * A_SPL)     // 26112 : one buffer (3 planes)
#define LDS_BYTES (2 * ABUF)     // 52224 : double-buffered -> 2 blocks/CU

// Workspace layout:
//   [0, 786432)            : B planes in frag layout (short8 units)
//   [786432, 786432+8MB)   : f64 logits [T_TOKENS][NE]  (split mode only)
#define WS_B_BYTES  786432
#define WS_LG_OFF   786432
#define WS_NEEDED   (WS_LG_OFF + (size_t)T_TOKENS * NE * 8)

typedef float    f32x4  __attribute__((ext_vector_type(4)));
typedef short    short8 __attribute__((ext_vector_type(8)));
typedef unsigned uint4v __attribute__((ext_vector_type(4)));

#define MFMA16(A, B, C) __builtin_amdgcn_mfma_f32_16x16x32_bf16((A), (B), (C), 0, 0, 0)

// RNE f2bf (probe only)
static __device__ __forceinline__ unsigned short f2bf(float x) {
    unsigned u = __builtin_bit_cast(unsigned, x);
    return (unsigned short)((u + 0x7FFFu + ((u >> 16) & 1u)) >> 16);
}

// 3-plane bf16 split of 8 floats, packed as 3 x uint4 (bit-identical to R4-R6).
static __device__ __forceinline__ void split8(const float4 v0, const float4 v1,
                                              uint4v& p0, uint4v& p1, uint4v& p2)
{
    const float x[8] = {v0.x, v0.y, v0.z, v0.w, v1.x, v1.y, v1.z, v1.w};
    #pragma unroll
    for (int j = 0; j < 4; ++j) {
        const float xe = x[2 * j], xo = x[2 * j + 1];
        const unsigned ue  = __builtin_bit_cast(unsigned, xe);
        const unsigned m0e = (ue + 0x8000u) & 0xFFFF0000u;
        const float    r1e = xe - __builtin_bit_cast(float, m0e);
        const unsigned u1e = __builtin_bit_cast(unsigned, r1e);
        const unsigned m1e = (u1e + 0x8000u) & 0xFFFF0000u;
        const float    r2e = r1e - __builtin_bit_cast(float, m1e);
        const unsigned u2e = __builtin_bit_cast(unsigned, r2e);
        const unsigned uo  = __builtin_bit_cast(unsigned, xo);
        const unsigned m0o = (uo + 0x8000u) & 0xFFFF0000u;
        const float    r1o = xo - __builtin_bit_cast(float, m0o);
        const unsigned u1o = __builtin_bit_cast(unsigned, r1o);
        const unsigned m1o = (u1o + 0x8000u) & 0xFFFF0000u;
        const float    r2o = r1o - __builtin_bit_cast(float, m1o);
        const unsigned u2o = __builtin_bit_cast(unsigned, r2o);
        p0[j] = m0o | (m0e >> 16);
        p1[j] = m1o | (m1e >> 16);
        p2[j] = (u2o & 0xFFFF0000u) | (u2e >> 16);
    }
}

// ---- pre-pass: split weight once into 3 bf16 planes in B-frag layout ----
__global__ __launch_bounds__(256) void split_weight_kernel(
    const float* __restrict__ weight, uint4v* __restrict__ ws)
{
    const int n = blockIdx.x;      // expert 0..63
    const int o = threadIdx.x;     // k-octet 0..255
    const float4 w0 = *(const float4*)&weight[(size_t)n * HID + o * 8];
    const float4 w1 = *(const float4*)&weight[(size_t)n * HID + o * 8 + 4];
    uint4v p0, p1, p2;
    split8(w0, w1, p0, p1, p2);
    const int t    = o >> 2;
    const int lane = (o & 3) * 16 + (n & 15);
    const int e    = n >> 4;
    const int base = t * 256 + e * 64 + lane;
    ws[base]         = p0;
    ws[base + 16384] = p1;
    ws[base + 32768] = p2;
}

// ---- main GEMM kernel. FUSED=true keeps the R6 in-kernel top-k (fallback
//      if workspace is too small); FUSED=false writes f64 logits to ws and
//      leaves top-k to topk_kernel. K-loop identical except B-prefetch depth 2.
template<bool FUSED>
__global__ __launch_bounds__(256, 2) void router_kernel(
    const float* __restrict__ hidden,   // [T_TOKENS, HID] f32
    const short8* __restrict__ bfrag,   // pre-split B planes (frag layout)
    double* __restrict__ lgws,          // [T_TOKENS, NE] f64 (split mode)
    float* __restrict__ out_logits,     // [T_TOKENS, NE]
    float* __restrict__ out_vals,       // [T_TOKENS, TOPK]
    float* __restrict__ out_idxf)       // [T_TOKENS, TOPK]
{
    __shared__ __align__(16) char smem[LDS_BYTES];
    double (*lg)[NE + 1] = reinterpret_cast<double(*)[NE + 1]>(smem);

    const int tid  = threadIdx.x;
    const int tok0 = blockIdx.x * TM;
    const int lane = tid & 63;
    const int wave = tid >> 6;   // 0..3 == expert tile of this wave

    const int fr = lane & 15;
    const int fk = lane >> 4;

    // ---- runtime D-layout probe (verified R3-R7) ----
    int rowmap[4], colmap[4];
    {
        const unsigned short mb = f2bf((float)fr);
        const unsigned short ob = f2bf(0.03125f);
        short8 vm, vo;
        #pragma unroll
        for (int j = 0; j < 8; ++j) { vm[j] = (short)mb; vo[j] = (short)ob; }
        const f32x4 z = {0.f, 0.f, 0.f, 0.f};
        const f32x4 pr = MFMA16(vm, vo, z);
        const f32x4 pc = MFMA16(vo, vm, z);
        #pragma unroll
        for (int i = 0; i < 4; ++i) {
            rowmap[i] = (int)(pr[i] + 0.5f);
            colmap[i] = (int)(pc[i] + 0.5f);
        }
    }

    // A staging map (R6-verified): 32 rows x 8 threads x 16 consecutive f32
    const int ar   = tid >> 3;
    const int ac16 = (tid & 7) * 16;
    const float* aG = hidden + (size_t)(tok0 + ar) * HID + ac16;
    const int aWOff = ar * RSTR + ac16 * 2;      // bytes within a buffer

    // B frag pointer: this wave's expert tile
    const short8* bP = bfrag + wave * 64 + lane;

    // A frag read bases (bytes within buffer) for the 2 token-frags
    const int aOff0 = fr * RSTR + fk * 16;
    const int aOff1 = (16 + fr) * RSTR + fk * 16;

    const f32x4 z4 = {0.f, 0.f, 0.f, 0.f};
    f32x4 acch[2] = {z4, z4};            // a0*b0 per token-frag
    f32x4 accl[2] = {z4, z4};            // corrections per token-frag
    double accd[2][4] = {{0, 0, 0, 0}, {0, 0, 0, 0}};

    float4 pa[4];
    short8 Bcur0, Bcur1, Bcur2;          // B planes, k-step t
    short8 Bnx0, Bnx1, Bnx2;             // B planes, k-step t+1

    // ---- prologue: stage chunk 0 + preload B(t=0), B(t=1) ----
    {
        #pragma unroll
        for (int q = 0; q < 4; ++q) pa[q] = *(const float4*)(aG + 4 * q);
        uint4v p0, p1, p2;
        char* aW = smem + aWOff;
        split8(pa[0], pa[1], p0, p1, p2);
        *(uint4v*)(aW            ) = p0;
        *(uint4v*)(aW +   A_SPL  ) = p1;
        *(uint4v*)(aW + 2*A_SPL  ) = p2;
        split8(pa[2], pa[3], p0, p1, p2);
        *(uint4v*)(aW             + 16) = p0;
        *(uint4v*)(aW +   A_SPL   + 16) = p1;
        *(uint4v*)(aW + 2*A_SPL   + 16) = p2;
    }
    Bcur0 = bP[0];
    Bcur1 = bP[16384];
    Bcur2 = bP[32768];
    Bnx0  = bP[256];
    Bnx1  = bP[256 + 16384];
    Bnx2  = bP[256 + 32768];
    __syncthreads();

    for (int c = 0; c < NCH; ++c) {
        const char* bufc = smem + (c & 1) * ABUF;

        // A frags for st=0
        short8 A00 = *(const short8*)(bufc + aOff0);
        short8 A01 = *(const short8*)(bufc + A_SPL + aOff0);
        short8 A02 = *(const short8*)(bufc + 2 * A_SPL + aOff0);
        short8 A10 = *(const short8*)(bufc + aOff1);
        short8 A11 = *(const short8*)(bufc + A_SPL + aOff1);
        short8 A12 = *(const short8*)(bufc + 2 * A_SPL + aOff1);

        // T14: issue next chunk's A global loads (hide under MFMA phase)
        if (c + 1 < NCH) {
            const int off = (c + 1) * BK;
            #pragma unroll
            for (int q = 0; q < 4; ++q) pa[q] = *(const float4*)(aG + off + 4 * q);
        }

        // ---- 4 k-steps; A 1-step pipeline, B 2-step pipeline ----
        #pragma unroll
        for (int st = 0; st < 4; ++st) {
            short8 An00, An01, An02, An10, An11, An12;
            if (st < 3) {
                const int ao = (st + 1) * 64;
                An00 = *(const short8*)(bufc + aOff0 + ao);
                An01 = *(const short8*)(bufc + A_SPL + aOff0 + ao);
                An02 = *(const short8*)(bufc + 2 * A_SPL + aOff0 + ao);
                An10 = *(const short8*)(bufc + aOff1 + ao);
                An11 = *(const short8*)(bufc + A_SPL + aOff1 + ao);
                An12 = *(const short8*)(bufc + 2 * A_SPL + aOff1 + ao);
            }
            // B(t+2): no LDS/barrier dependency -> always safe to prefetch
            short8 B20 = Bnx0, B21 = Bnx1, B22 = Bnx2;
            if (c < NCH - 1 || st < 2) {
                const int t2 = (c * 4 + st + 2) * 256;
                B20 = bP[t2];
                B21 = bP[t2 + 16384];
                B22 = bP[t2 + 32768];
            }

            // 12 MFMAs on current regs (R6-verified ordering)
            acch[0] = MFMA16(A00, Bcur0, acch[0]);
            accl[0] = MFMA16(A00, Bcur1, accl[0]);
            accl[0] = MFMA16(A01, Bcur0, accl[0]);
            accl[0] = MFMA16(A01, Bcur1, accl[0]);
            accl[0] = MFMA16(A00, Bcur2, accl[0]);
            accl[0] = MFMA16(A02, Bcur0, accl[0]);
            acch[1] = MFMA16(A10, Bcur0, acch[1]);
            accl[1] = MFMA16(A10, Bcur1, accl[1]);
            accl[1] = MFMA16(A11, Bcur0, accl[1]);
            accl[1] = MFMA16(A11, Bcur1, accl[1]);
            accl[1] = MFMA16(A10, Bcur2, accl[1]);
            accl[1] = MFMA16(A12, Bcur0, accl[1]);

            if (st < 3) {
                A00 = An00; A01 = An01; A02 = An02;
                A10 = An10; A11 = An11; A12 = An12;
            }
            Bcur0 = Bnx0; Bcur1 = Bnx1; Bcur2 = Bnx2;
            Bnx0  = B20;  Bnx1  = B21;  Bnx2  = B22;
        }

        // ---- span dump: hi-term f32 acc -> f64, reset ----
        #pragma unroll
        for (int f = 0; f < 2; ++f) {
            #pragma unroll
            for (int i = 0; i < 4; ++i) accd[f][i] += (double)acch[f][i];
            acch[f] = z4;
        }

        // ---- split + write next chunk into the other buffer, ONE barrier ----
        if (c + 1 < NCH) {
            uint4v p0, p1, p2;
            char* aW = smem + ((c & 1) ^ 1) * ABUF + aWOff;
            split8(pa[0], pa[1], p0, p1, p2);
            *(uint4v*)(aW            ) = p0;
            *(uint4v*)(aW +   A_SPL  ) = p1;
            *(uint4v*)(aW + 2*A_SPL  ) = p2;
            split8(pa[2], pa[3], p0, p1, p2);
            *(uint4v*)(aW             + 16) = p0;
            *(uint4v*)(aW +   A_SPL   + 16) = p1;
            *(uint4v*)(aW + 2*A_SPL   + 16) = p2;
        }
        __syncthreads();
    }

    // ---- epilogue ----
    if constexpr (!FUSED) {
        // split mode: write f32 logits + f64 logits to workspace; done.
        #pragma unroll
        for (int f = 0; f < 2; ++f) {
            #pragma unroll
            for (int i = 0; i < 4; ++i) {
                const int trow = f * 16 + rowmap[i];
                const int tok  = tok0 + trow;
                const int e0   = wave * 16 + colmap[i];
                const double l0 = accd[f][i] + (double)accl[f][i];
                out_logits[(size_t)tok * NE + e0] = (float)l0;
                lgws[(size_t)tok * NE + e0]       = l0;
            }
        }
    } else {
        // fused fallback: R6-verified in-kernel top-8
        #pragma unroll
        for (int f = 0; f < 2; ++f) {
            #pragma unroll
            for (int i = 0; i < 4; ++i) {
                const int trow = f * 16 + rowmap[i];
                const int tok  = tok0 + trow;
                const int e0   = wave * 16 + colmap[i];
                const double l0 = accd[f][i] + (double)accl[f][i];
                out_logits[(size_t)tok * NE + e0] = (float)l0;
                lg[trow][e0] = l0;
            }
        }
        __syncthreads();

        for (int tt = wave; tt < TM; tt += 4) {
            double cur = lg[tt][lane];
            double first = 0.0;
            float  s = 0.f, myv = 0.f;
            int myi = 0;
            #pragma unroll
            for (int i = 0; i < TOPK; ++i) {
                double mv = cur;
                #pragma unroll
                for (int off = 32; off; off >>= 1) {
                    const double ov = __shfl_xor(mv, off);
                    mv = ov > mv ? ov : mv;
                }
                const unsigned long long m = __ballot(cur == mv);
                const int mi = __ffsll(m) - 1;
                if (i == 0) first = mv;
                const float e = expf((float)(mv - first));
                s += e;
                if (lane == i)  { myv = e; myi = mi; }
                if (lane == mi) cur = -INFINITY;
            }
            if (lane < TOPK) {
                const int tok = tok0 + tt;
                out_vals[(size_t)tok * TOPK + lane] = myv / s;
                out_idxf[(size_t)tok * TOPK + lane] = (float)myi;
            }
        }
    }
}

// ---- top-8 kernel (split mode): 1 token per wave, f64 logits from ws.
//      Same reduce/tie-break/softmax semantics as the R3-R7 fused epilogue.
__global__ __launch_bounds__(256) void topk_kernel(
    const double* __restrict__ lgws,
    float* __restrict__ out_vals,
    float* __restrict__ out_idxf)
{
    const int lane = threadIdx.x & 63;
    const int gw   = (blockIdx.x * 256 + threadIdx.x) >> 6;  // 0..4095
    for (int tok = gw; tok < T_TOKENS; tok += 4096) {
        double cur = lgws[(size_t)tok * NE + lane];
        double first = 0.0;
        float  s = 0.f, myv = 0.f;
        int myi = 0;
        #pragma unroll
        for (int i = 0; i < TOPK; ++i) {
            double mv = cur;
            #pragma unroll
            for (int off = 32; off; off >>= 1) {
                const double ov = __shfl_xor(mv, off);
                mv = ov > mv ? ov : mv;
            }
            const unsigned long long m = __ballot(cur == mv);
            const int mi = __ffsll(m) - 1;
            if (i == 0) first = mv;
            const float e = expf((float)(mv - first));
            s += e;
            if (lane == i)  { myv = e; myi = mi; }
            if (lane == mi) cur = -INFINITY;
        }
        if (lane < TOPK) {
            out_vals[(size_t)tok * TOPK + lane] = myv / s;
            out_idxf[(size_t)tok * TOPK + lane] = (float)myi;
        }
    }
}

extern "C" void kernel_launch(void* const* d_in, const int* in_sizes, int n_in,
                              void* d_out, int out_size, void* d_ws, size_t ws_size,
                              hipStream_t stream) {
    const float* hidden = (const float*)d_in[0];   // [16384, 2048] f32
    const float* weight = (const float*)d_in[1];   // [64, 2048] f32

    float* out        = (float*)d_out;
    float* out_logits = out;
    float* out_vals   = out + (size_t)T_TOKENS * NE;
    float* out_idxf   = out + (size_t)T_TOKENS * NE + (size_t)T_TOKENS * TOPK;

    uint4v* ws   = (uint4v*)d_ws;
    double* lgws = (double*)((char*)d_ws + WS_LG_OFF);

    hipLaunchKernelGGL(split_weight_kernel, dim3(NE), dim3(256), 0, stream,
                       weight, ws);

    if (ws_size >= WS_NEEDED) {
        hipLaunchKernelGGL((router_kernel<false>), dim3(T_TOKENS / TM), dim3(256),
                           0, stream, hidden, (const short8*)ws, lgws,
                           out_logits, out_vals, out_idxf);
        hipLaunchKernelGGL(topk_kernel, dim3(1024), dim3(256), 0, stream,
                           lgws, out_vals, out_idxf);
    } else {
        hipLaunchKernelGGL((router_kernel<true>), dim3(T_TOKENS / TM), dim3(256),
                           0, stream, hidden, (const short8*)ws, (double*)nullptr,
                           out_logits, out_vals, out_idxf);
    }
}